// Round 5
// baseline (389.760 us; speedup 1.0000x reference)
//
#include <hip/hip_runtime.h>
#include <hip/hip_bf16.h>

#define NREL 53
#define FEAT 690
#define NBAGS 512
#define SMAX 128
#define K2 106        // 53 (m) + 53 (r_embed) projection columns
#define KPAD 704      // FEAT padded to 22*32
#define NT 22         // K-steps of 32
#define LDSTR 40      // A-LDS row stride in shorts (80 B)
#define WSTR 140      // k_finish LDS row stride in floats (560 B, 16B-aligned)

typedef short bf16x8 __attribute__((ext_vector_type(8)));
typedef short short4v __attribute__((ext_vector_type(4)));
typedef short short8v __attribute__((ext_vector_type(8)));
typedef float f32x4 __attribute__((ext_vector_type(4)));

__device__ __forceinline__ short f2bf(float x) {   // RNE, finite inputs
    union { float f; unsigned u; } c; c.f = x;
    unsigned r = c.u + 0x7fffu + ((c.u >> 16) & 1u);
    return (short)(r >> 16);
}

// packed f32x4 -> bf16x4 via v_cvt_pk_bf16_f32
__device__ __forceinline__ short4v pack4(float a, float b, float c, float d) {
    __hip_bfloat162 p0 = __float22bfloat162_rn(make_float2(a, b));
    __hip_bfloat162 p1 = __float22bfloat162_rn(make_float2(c, d));
    union { __hip_bfloat162 h; short2 s; } u0, u1;
    u0.h = p0; u1.h = p1;
    short4v w = {u0.s.x, u0.s.y, u1.s.x, u1.s.y};
    return w;
}

// ---------------- kernel 1: m[r][g] = sum_f r_embed[r][f] * att_W[r][f][g] ----------------
#define FCH 30
__global__ __launch_bounds__(256) void k_m(const float* __restrict__ r_embed,
                                           const float* __restrict__ att_W,
                                           float* __restrict__ m_ws) {
    const int gc = blockIdx.x, fc = blockIdx.y, r = blockIdx.z;
    const int g = gc * 512 + threadIdx.x * 2;
    const int f0 = fc * FCH;
    __shared__ float re[FCH];
    if (threadIdx.x < FCH) re[threadIdx.x] = r_embed[r * FEAT + f0 + threadIdx.x];
    __syncthreads();
    if (g >= FEAT) return;
    const float* aw = att_W + (size_t)r * FEAT * FEAT + (size_t)f0 * FEAT + g;
    float ax = 0.f, ay = 0.f;
    #pragma unroll
    for (int j = 0; j < FCH; ++j) {
        const float2 t = *(const float2*)&aw[(size_t)j * FEAT];
        ax += re[j] * t.x;
        ay += re[j] * t.y;
    }
    atomicAdd(&m_ws[r * FEAT + g], ax);
    atomicAdd(&m_ws[r * FEAT + g + 1], ay);
}

// ---------------- kernel 1b: Bws[n][f] bf16; n<53: m, 53..105: r_embed, else/pad: 0 -------
__global__ __launch_bounds__(256) void k_prep(const float* __restrict__ m_ws,
                                              const float* __restrict__ r_embed,
                                              short* __restrict__ Bws) {
    const int n = blockIdx.x;          // 0..127
    for (int f = threadIdx.x; f < KPAD; f += 256) {
        float v = 0.f;
        if (f < FEAT) {
            if (n < NREL)    v = m_ws[n * FEAT + f];
            else if (n < K2) v = r_embed[(n - NREL) * FEAT + f];
        }
        Bws[n * KPAD + f] = f2bf(v);
    }
}

// ---------------- kernel 2: projT[b][k][s] = feat[b,s,:] . M2[k,:]  (bf16 MFMA) ----------
// One block per bag: 128(s) x 128(k), 4 waves x (64x64). A: LDS dbuf; B: global->reg.
__global__ __launch_bounds__(256) void k_proj(const float* __restrict__ features,
                                              const int* __restrict__ lengths,
                                              const short* __restrict__ Bws,
                                              float* __restrict__ projT) {
    const int b = blockIdx.x;
    const int L = lengths[b];
    __shared__ short Ash[2][128 * LDSTR];   // 20.5 KB
    const int tid = threadIdx.x;
    const int wave = tid >> 6, lane = tid & 63;
    const int wr = (wave >> 1) * 64, wc = (wave & 1) * 64;
    const int r16 = lane & 15, g = lane >> 4;
    const float* fb = features + (size_t)b * SMAX * FEAT;
    const bool active = (wr < L);

    f32x4 acc[4][4];
    #pragma unroll
    for (int m = 0; m < 4; ++m)
        #pragma unroll
        for (int n = 0; n < 4; ++n) acc[m][n] = (f32x4)0.f;

    const int srow = tid >> 3;          // A staging row within slab
    const int fo   = (tid & 7) * 4;     // A staging col quad (floats)

    // ---- prologue: stage kt=0 A into buf 0; load kt=0 B frags to regs
    #pragma unroll
    for (int it = 0; it < 4; ++it) {
        if (it * 32 < L) {
            const int s = it * 32 + srow;
            const float2 v0 = *(const float2*)&fb[(size_t)s * FEAT + fo];
            const float2 v1 = *(const float2*)&fb[(size_t)s * FEAT + fo + 2];
            *(short4v*)&Ash[0][s * LDSTR + fo] = pack4(v0.x, v0.y, v1.x, v1.y);
        }
    }
    short8v bcur[4], bnext[4];
    if (active) {
        #pragma unroll
        for (int n = 0; n < 4; ++n)
            bcur[n] = *(const short8v*)&Bws[(size_t)(wc + n * 16 + r16) * KPAD + g * 8];
    }
    __syncthreads();

    int cur = 0;
    for (int kt = 0; kt < NT; ++kt) {
        const bool have_next = (kt + 1 < NT);
        float2 av[4][2];
        if (have_next) {
            const int k0n = (kt + 1) * 32;
            const bool lastn = (kt + 1 == NT - 1);
            #pragma unroll
            for (int it = 0; it < 4; ++it) {
                if (it * 32 < L) {
                    const int s = it * 32 + srow;
                    const int f0 = k0n + fo;
                    const float* p = fb + (size_t)s * FEAT + f0;
                    if (!lastn) {
                        av[it][0] = *(const float2*)p;
                        av[it][1] = *(const float2*)(p + 2);
                    } else {
                        av[it][0] = (f0 + 1 < FEAT) ? *(const float2*)p       : make_float2(0.f, 0.f);
                        av[it][1] = (f0 + 3 < FEAT) ? *(const float2*)(p + 2) : make_float2(0.f, 0.f);
                    }
                }
            }
            if (active) {
                #pragma unroll
                for (int n = 0; n < 4; ++n)
                    bnext[n] = *(const short8v*)&Bws[(size_t)(wc + n * 16 + r16) * KPAD + k0n + g * 8];
            }
        }

        // ---- compute on Ash[cur] x bcur
        if (active) {
            bf16x8 af[4];
            #pragma unroll
            for (int m = 0; m < 4; ++m)
                af[m] = *(const bf16x8*)&Ash[cur][(wr + m * 16 + r16) * LDSTR + g * 8];
            #pragma unroll
            for (int m = 0; m < 4; ++m)
                #pragma unroll
                for (int n = 0; n < 4; ++n)
                    acc[m][n] = __builtin_amdgcn_mfma_f32_16x16x32_bf16(af[m], (bf16x8)bcur[n], acc[m][n], 0, 0, 0);
        }

        // ---- write next A tile into buf[cur^1]; rotate B regs
        if (have_next) {
            #pragma unroll
            for (int it = 0; it < 4; ++it) {
                if (it * 32 < L) {
                    const int s = it * 32 + srow;
                    *(short4v*)&Ash[cur ^ 1][s * LDSTR + fo] =
                        pack4(av[it][0].x, av[it][0].y, av[it][1].x, av[it][1].y);
                }
            }
            if (active) {
                #pragma unroll
                for (int n = 0; n < 4; ++n) bcur[n] = bnext[n];
            }
        }
        __syncthreads();
        cur ^= 1;
    }

    // ---- epilogue: C/D layout col=lane&15, row=(lane>>4)*4+reg
    if (active) {
        float* pT = projT + (size_t)b * K2 * SMAX;
        #pragma unroll
        for (int m = 0; m < 4; ++m) {
            const int s0 = wr + m * 16 + g * 4;
            if (s0 < L) {
                #pragma unroll
                for (int n = 0; n < 4; ++n) {
                    const int k = wc + n * 16 + r16;
                    if (k < K2) *(f32x4*)&pT[k * SMAX + s0] = acc[m][n];
                }
            }
        }
    }
}

// ---------------- kernel 3: per-bag softmax + contraction + log_softmax + max ------------
__global__ __launch_bounds__(256) void k_finish(const float* __restrict__ projT,
                                                const int* __restrict__ lengths,
                                                const float* __restrict__ r_bias,
                                                float* __restrict__ out) {
    const int b = blockIdx.x;
    const int L = lengths[b];
    const int Lp = ((L + 3) >> 2) << 2;   // ceil4(L)
    __shared__ float wS[56 * WSTR];       // [r][s], 31.4 KB
    __shared__ float pRs[56 * WSTR];      // [k][s], 31.4 KB
    __shared__ float sc[NREL * 56];
    __shared__ float lse[NREL];
    const int tid = threadIdx.x;
    const int wv = tid >> 6, lane = tid & 63;
    const float* pb = projT + (size_t)b * K2 * SMAX;

    // stage pRs[k][s] = projT[b][53+k][s]  (float4 rows, coalesced)
    for (int idx = tid; idx < NREL * 32; idx += 256) {
        const int k = idx >> 5, s4 = (idx & 31) * 4;
        *(float4*)&pRs[k * WSTR + s4] = *(const float4*)&pb[(size_t)(NREL + k) * SMAX + s4];
    }
    // masked softmax over s per relation row (logit rows from global); fold *0.5; zero-pad to Lp
    for (int r = wv; r < NREL; r += 4) {
        const float* row = pb + (size_t)r * SMAX;
        float v0 = (lane < L)      ? row[lane]      : -1e30f;
        float v1 = (lane + 64 < L) ? row[lane + 64] : -1e30f;
        float mx = fmaxf(v0, v1);
        for (int o = 32; o; o >>= 1) mx = fmaxf(mx, __shfl_xor(mx, o));
        float e0 = (lane < L)      ? __expf(v0 - mx) : 0.f;
        float e1 = (lane + 64 < L) ? __expf(v1 - mx) : 0.f;
        float sm = e0 + e1;
        for (int o = 32; o; o >>= 1) sm += __shfl_xor(sm, o);
        const float inv = 0.5f / sm;
        if (lane < Lp)      wS[r * WSTR + lane]      = e0 * inv;   // 0 for lane>=L
        if (lane + 64 < Lp) wS[r * WSTR + lane + 64] = e1 * inv;
    }
    __syncthreads();

    // sc[r][k] = sum_s wS[r][s] * pRs[k][s] + bias[k]; 4x4 tiles, s-vectorized float4
    {
        const int ty = tid >> 4, tx = tid & 15;
        if (ty < 14 && tx < 14) {
            const int rr = ty * 4, kk = tx * 4;
            float a4[4][4] = {};
            for (int s = 0; s < Lp; s += 4) {
                float4 aa[4], bb[4];
                #pragma unroll
                for (int i = 0; i < 4; ++i) aa[i] = *(const float4*)&wS[(rr + i) * WSTR + s];
                #pragma unroll
                for (int n = 0; n < 4; ++n) bb[n] = *(const float4*)&pRs[(kk + n) * WSTR + s];
                #pragma unroll
                for (int i = 0; i < 4; ++i)
                    #pragma unroll
                    for (int n = 0; n < 4; ++n)
                        a4[i][n] += aa[i].x * bb[n].x + aa[i].y * bb[n].y
                                  + aa[i].z * bb[n].z + aa[i].w * bb[n].w;
            }
            #pragma unroll
            for (int i = 0; i < 4; ++i) {
                const int r = rr + i;
                if (r < NREL) {
                    #pragma unroll
                    for (int n = 0; n < 4; ++n) {
                        const int k = kk + n;
                        if (k < NREL) sc[r * 56 + k] = a4[i][n] + r_bias[k];
                    }
                }
            }
        }
    }
    __syncthreads();

    // per-row logsumexp over k
    for (int r = wv; r < NREL; r += 4) {
        const float v = (lane < NREL) ? sc[r * 56 + lane] : -1e30f;
        float mx = v;
        for (int o = 32; o; o >>= 1) mx = fmaxf(mx, __shfl_xor(mx, o));
        float e = (lane < NREL) ? __expf(v - mx) : 0.f;
        for (int o = 32; o; o >>= 1) e += __shfl_xor(e, o);
        if (lane == 0) lse[r] = mx + __logf(e);
    }
    __syncthreads();

    if (tid < NREL) {
        float best = -1e30f;
        for (int r = 0; r < NREL; ++r) best = fmaxf(best, sc[r * 56 + tid] - lse[r]);
        out[b * NREL + tid] = best;
    }
}

extern "C" void kernel_launch(void* const* d_in, const int* in_sizes, int n_in,
                              void* d_out, int out_size, void* d_ws, size_t ws_size,
                              hipStream_t stream) {
    const float* features = (const float*)d_in[0];   // [512,128,690]
    const int*   lengths  = (const int*)d_in[1];     // [512]
    const float* r_embed  = (const float*)d_in[2];   // [53,690]
    const float* r_bias   = (const float*)d_in[3];   // [53]
    const float* att_W    = (const float*)d_in[4];   // [53,690,690]
    float* out = (float*)d_out;                      // [512,53]

    float* m_ws  = (float*)d_ws;                                 // 146 KB
    short* Bws   = (short*)((char*)d_ws + (1 << 18));            // 176 KB bf16 B-matrix
    float* projT = (float*)((char*)d_ws + (1 << 19));            // 27.8 MB

    hipMemsetAsync(m_ws, 0, NREL * FEAT * sizeof(float), stream);

    dim3 g1(2, 23, NREL);
    k_m<<<g1, 256, 0, stream>>>(r_embed, att_W, m_ws);
    k_prep<<<128, 256, 0, stream>>>(m_ws, r_embed, Bws);
    k_proj<<<NBAGS, 256, 0, stream>>>(features, lengths, Bws, projT);
    k_finish<<<NBAGS, 256, 0, stream>>>(projT, lengths, r_bias, out);
}